// Round 14
// baseline (275.898 us; speedup 1.0000x reference)
//
#include <hip/hip_runtime.h>

#define BC 88                        // B*C channels
#define NVOX 262144                  // 64^3
#define KBINS 20
#define THREADS 256
#define NBLOCKS 2048                 // 8/CU, zero tail (best geometry, R6/R7)
#define CPB 11                       // chunks (1024 elems = 256 float4) per block
#define CPC 256                      // chunks per channel
#define HSTRIDE 23                   // 22 slots + pad; gcd(23,32)=1
#define NSUB 64
#define ROWSET (NSUB * HSTRIDE)
#define FH (BC * KBINS)              // 1760 histogram ints

// R7's proven kernel (best e2e 43.4us, absmax 0.0) + fused last-block finalize
// (saves the 3rd dispatch + gap; R12's slow-final trap avoided: reads here are
// coalesced, ~15 loads/thread).
__global__ void __launch_bounds__(THREADS, 4)
binloss_main(const float* __restrict__ inp, const float* __restrict__ tar,
             const float* __restrict__ br, int* __restrict__ g_hist,
             int* __restrict__ cnt, float* __restrict__ partials,
             float* __restrict__ out)
{
    __shared__ int    rows[2 * ROWSET];       // seg-1 / seg-2 channel rowsets
    __shared__ float  wsum[THREADS / 64];
    __shared__ int    amlast;
    __shared__ double r1[THREADS], r2[THREADS];

    const int tid = threadIdx.x;
    for (int i = tid; i < 2 * ROWSET; i += THREADS) rows[i] = 0;

    // uniform scalar loads; +1 folded so (int) truncation == floor
    const float e0     = br[0];
    const float eK     = br[2 * KBINS - 1];
    const float inv_w  = (float)KBINS / (eK - e0);
    const float shift1 = 1.0f - e0 * inv_w;
    const float tmax   = 21.5f;
    __syncthreads();

    const int fc  = blockIdx.x * CPB;
    const int ch0 = fc >> 8;                  // / CPC
    const int rem = fc & (CPC - 1);
    const int n1  = (rem + CPB > CPC) ? (CPC - rem) : CPB;   // chunks in ch0

    const float4* pa = (const float4*)inp + (size_t)fc * 256 + tid;
    const float4* pb = (const float4*)tar + (size_t)fc * 256 + tid;

    int* r0 = &rows[(tid & 63) * HSTRIDE];
    int* rr1 = r0 + ROWSET;

    float s_lin = 0.f, s_quad = 0.f;

    auto proc = [&](float4 a, float4 b, int* rw) {
#pragma unroll
        for (int q = 0; q < 4; ++q) {
            float av = (&a.x)[q], bv = (&b.x)[q];
            float d = fabsf(av - bv);
            s_lin += fmaxf(d, 1.0f);                     // -1 hoisted out
            float m = fminf(d, 1.0f);
            s_quad  = __builtin_fmaf(m, m, s_quad);
            int sa = (int)__builtin_amdgcn_fmed3f(__builtin_fmaf(av, inv_w, shift1), 0.0f, tmax);
            int sb = (int)__builtin_amdgcn_fmed3f(__builtin_fmaf(bv, inv_w, shift1), 0.0f, tmax);
            atomicAdd(&rw[sa], 1);                       // slots 0,21 = trash
            atomicAdd(&rw[sb], -1);
        }
    };

    // batched issue (R7): 16 loads up-front, 6 mid-stream
    float4 A0 = pa[0 * 256], A1 = pa[1 * 256], A2 = pa[2 * 256], A3 = pa[3 * 256];
    float4 B0 = pb[0 * 256], B1 = pb[1 * 256], B2 = pb[2 * 256], B3 = pb[3 * 256];
    float4 C0 = pa[4 * 256], C1 = pa[5 * 256], C2 = pa[6 * 256], C3 = pa[7 * 256];
    float4 D0 = pb[4 * 256], D1 = pb[5 * 256], D2 = pb[6 * 256], D3 = pb[7 * 256];

    proc(A0, B0, (0 < n1) ? r0 : rr1);
    proc(A1, B1, (1 < n1) ? r0 : rr1);
    proc(A2, B2, (2 < n1) ? r0 : rr1);
    proc(A3, B3, (3 < n1) ? r0 : rr1);

    float4 E0 = pa[8 * 256], E1 = pa[9 * 256], E2 = pa[10 * 256];
    float4 F0 = pb[8 * 256], F1 = pb[9 * 256], F2 = pb[10 * 256];

    proc(C0, D0, (4 < n1) ? r0 : rr1);
    proc(C1, D1, (5 < n1) ? r0 : rr1);
    proc(C2, D2, (6 < n1) ? r0 : rr1);
    proc(C3, D3, (7 < n1) ? r0 : rr1);
    proc(E0, F0, (8 < n1) ? r0 : rr1);
    proc(E1, F1, (9 < n1) ? r0 : rr1);
    proc(E2, F2, (10 < n1) ? r0 : rr1);

    // SmoothL1 wave(64) + cross-wave reduce
    float sl1 = (s_lin - (float)(CPB * 4)) + 0.5f * s_quad;
#pragma unroll
    for (int off = 32; off > 0; off >>= 1) sl1 += __shfl_down(sl1, off, 64);
    if ((tid & 63) == 0) wsum[tid >> 6] = sl1;
    __syncthreads();

    if (tid == 0)
        partials[blockIdx.x] = wsum[0] + wsum[1] + wsum[2] + wsum[3];

    // fold both row-sets: set 0 -> ch0, set 1 -> ch0+1 (zero unless boundary)
    if (tid < 160) {
        const int set = tid / 80, t2 = tid % 80;
        const int bin = t2 % KBINS, qr = t2 / KBINS;
        const int ch  = ch0 + set;
        if (ch < BC) {
            int s = 0;
#pragma unroll
            for (int r = qr * 16; r < qr * 16 + 16; ++r)
                s += rows[set * ROWSET + r * HSTRIDE + 1 + bin];
            if (s) atomicAdd(&g_hist[ch * KBINS + bin], s);
        }
    }

    // ---- fused finalize: last block to arrive reduces everything ----
    __threadfence();
    __syncthreads();
    if (tid == 0) amlast = (atomicAdd(cnt, 1) == NBLOCKS - 1);
    __syncthreads();
    if (!amlast) return;
    __threadfence();

    double s1 = 0.0, s2 = 0.0;
    for (int i = tid; i < NBLOCKS; i += THREADS) s1 += (double)partials[i];
    for (int i = tid; i < FH; i += THREADS) s2 += fabs((double)g_hist[i]);
    r1[tid] = s1; r2[tid] = s2;
    __syncthreads();
    for (int off = 128; off > 0; off >>= 1) {
        if (tid < off) { r1[tid] += r1[tid + off]; r2[tid] += r2[tid + off]; }
        __syncthreads();
    }
    if (tid == 0) {
        const double ntot  = (double)BC * (double)NVOX;
        double loss1 = r1[0] / ntot;
        double loss2 = r2[0] / ((double)NVOX * (double)FH);
        out[0] = (float)(0.5 * loss1 + 0.5 * loss2);
    }
}

extern "C" void kernel_launch(void* const* d_in, const int* in_sizes, int n_in,
                              void* d_out, int out_size, void* d_ws, size_t ws_size,
                              hipStream_t stream) {
    const float* inp = (const float*)d_in[0];
    const float* tar = (const float*)d_in[1];
    const float* br  = (const float*)d_in[2];

    int*   g_hist   = (int*)d_ws;                       // FH ints
    int*   cnt      = g_hist + FH;                      // 1 int completion counter
    float* partials = (float*)(cnt + 1);                // NBLOCKS floats

    // histogram + counter accumulated with atomics -> zero every call
    hipMemsetAsync(d_ws, 0, (FH + 1) * sizeof(int), stream);

    binloss_main<<<NBLOCKS, THREADS, 0, stream>>>(inp, tar, br, g_hist, cnt,
                                                  partials, (float*)d_out);
}

// Round 15
// 44.750 us; speedup vs baseline: 6.1653x; 6.1653x over previous
//
#include <hip/hip_runtime.h>

#define BC 88                        // B*C channels
#define NVOX 262144                  // 64^3
#define KBINS 20
#define THREADS 256
#define NBLOCKS 2048                 // 11 chunks per block covers 22528 chunks exactly
#define CPB 11                       // chunks (1024 elems = 256 float4) per block
#define CPC 256                      // chunks per channel
#define HSTRIDE 23                   // 22 slots + pad; gcd(23,32)=1
#define NSUB 64                      // per-lane rows (shared by 4 waves, atomic)
#define ROWSET (NSUB * HSTRIDE)

// R7 verbatim — best measured e2e (43.4us, absmax 0.0). 12 structurally
// distinct variants (R1-R14) all bound by the same ~5 TB/s stream floor;
// epilogue/fusion alternatives (R12 slot-final, R14 last-block fence) regress.
__global__ void __launch_bounds__(THREADS, 4)
binloss_main(const float* __restrict__ inp, const float* __restrict__ tar,
             const float* __restrict__ br, int* __restrict__ g_hist,
             float* __restrict__ partials)
{
    __shared__ int   rows[2 * ROWSET];        // two sets: seg-1 / seg-2 channel
    __shared__ float wsum[THREADS / 64];

    const int tid = threadIdx.x;
    for (int i = tid; i < 2 * ROWSET; i += THREADS) rows[i] = 0;

    // uniform scalar loads; +1 folded so (int) truncation == floor
    const float e0     = br[0];
    const float eK     = br[2 * KBINS - 1];
    const float inv_w  = (float)KBINS / (eK - e0);
    const float shift1 = 1.0f - e0 * inv_w;
    const float tmax   = 21.5f;
    __syncthreads();

    const int fc  = blockIdx.x * CPB;
    const int ch0 = fc >> 8;
    const int rem = fc & (CPC - 1);
    const int n1  = (rem + CPB > CPC) ? (CPC - rem) : CPB;   // chunks in channel ch0

    const float4* pa = (const float4*)inp + (size_t)fc * 256 + tid;
    const float4* pb = (const float4*)tar + (size_t)fc * 256 + tid;

    int* r0 = &rows[(tid & 63) * HSTRIDE];
    int* r1 = r0 + ROWSET;

    float s_lin = 0.f, s_quad = 0.f;

    auto proc = [&](float4 a, float4 b, int* rw) {
#pragma unroll
        for (int q = 0; q < 4; ++q) {
            float av = (&a.x)[q], bv = (&b.x)[q];
            float d = fabsf(av - bv);
            s_lin += fmaxf(d, 1.0f);                     // -1 hoisted out
            float m = fminf(d, 1.0f);
            s_quad  = __builtin_fmaf(m, m, s_quad);
            int sa = (int)__builtin_amdgcn_fmed3f(__builtin_fmaf(av, inv_w, shift1), 0.0f, tmax);
            int sb = (int)__builtin_amdgcn_fmed3f(__builtin_fmaf(bv, inv_w, shift1), 0.0f, tmax);
            atomicAdd(&rw[sa], 1);                       // slots 0,21 = trash
            atomicAdd(&rw[sb], -1);
        }
    };

    // ---- batched issue: 16 loads now (k=0..7), 6 more mid-stream ----
    float4 A0 = pa[0 * 256], A1 = pa[1 * 256], A2 = pa[2 * 256], A3 = pa[3 * 256];
    float4 B0 = pb[0 * 256], B1 = pb[1 * 256], B2 = pb[2 * 256], B3 = pb[3 * 256];
    float4 C0 = pa[4 * 256], C1 = pa[5 * 256], C2 = pa[6 * 256], C3 = pa[7 * 256];
    float4 D0 = pb[4 * 256], D1 = pb[5 * 256], D2 = pb[6 * 256], D3 = pb[7 * 256];

    proc(A0, B0, (0 < n1) ? r0 : r1);
    proc(A1, B1, (1 < n1) ? r0 : r1);
    proc(A2, B2, (2 < n1) ? r0 : r1);
    proc(A3, B3, (3 < n1) ? r0 : r1);

    float4 E0 = pa[8 * 256], E1 = pa[9 * 256], E2 = pa[10 * 256];
    float4 F0 = pb[8 * 256], F1 = pb[9 * 256], F2 = pb[10 * 256];

    proc(C0, D0, (4 < n1) ? r0 : r1);
    proc(C1, D1, (5 < n1) ? r0 : r1);
    proc(C2, D2, (6 < n1) ? r0 : r1);
    proc(C3, D3, (7 < n1) ? r0 : r1);
    proc(E0, F0, (8 < n1) ? r0 : r1);
    proc(E1, F1, (9 < n1) ? r0 : r1);
    proc(E2, F2, (10 < n1) ? r0 : r1);

    // SmoothL1 wave(64) + cross-wave reduce
    float sl1 = (s_lin - (float)(CPB * 4)) + 0.5f * s_quad;
#pragma unroll
    for (int off = 32; off > 0; off >>= 1) sl1 += __shfl_down(sl1, off, 64);
    if ((tid & 63) == 0) wsum[tid >> 6] = sl1;
    __syncthreads();

    if (tid == 0)
        partials[blockIdx.x] = wsum[0] + wsum[1] + wsum[2] + wsum[3];

    // fold both row-sets: set 0 -> ch0, set 1 -> ch0+1 (zero unless boundary)
    if (tid < 160) {
        const int set = tid / 80, t2 = tid % 80;
        const int bin = t2 % KBINS, qr = t2 / KBINS;
        const int ch  = ch0 + set;
        if (ch < BC) {
            int s = 0;
#pragma unroll
            for (int r = qr * 16; r < qr * 16 + 16; ++r)
                s += rows[set * ROWSET + r * HSTRIDE + 1 + bin];
            if (s) atomicAdd(&g_hist[ch * KBINS + bin], s);
        }
    }
}

__global__ void __launch_bounds__(256)
binloss_final(const int* __restrict__ g_hist, const float* __restrict__ partials,
              float* __restrict__ out)
{
    __shared__ double r1[256];
    __shared__ double r2[256];
    const int tid = threadIdx.x;
    double s1 = 0.0, s2 = 0.0;
    for (int i = tid; i < NBLOCKS; i += 256) s1 += (double)partials[i];
    for (int i = tid; i < BC * KBINS; i += 256) s2 += fabs((double)g_hist[i]);
    r1[tid] = s1; r2[tid] = s2;
    __syncthreads();
    for (int off = 128; off > 0; off >>= 1) {
        if (tid < off) { r1[tid] += r1[tid + off]; r2[tid] += r2[tid + off]; }
        __syncthreads();
    }
    if (tid == 0) {
        const double ntot  = (double)BC * (double)NVOX;
        double loss1 = r1[0] / ntot;
        double loss2 = r2[0] / ((double)NVOX * (double)(BC * KBINS));
        out[0] = (float)(0.5 * loss1 + 0.5 * loss2);
    }
}

extern "C" void kernel_launch(void* const* d_in, const int* in_sizes, int n_in,
                              void* d_out, int out_size, void* d_ws, size_t ws_size,
                              hipStream_t stream) {
    const float* inp = (const float*)d_in[0];
    const float* tar = (const float*)d_in[1];
    const float* br  = (const float*)d_in[2];

    int*   g_hist   = (int*)d_ws;
    float* partials = (float*)((char*)d_ws + BC * KBINS * sizeof(int));

    // histogram accumulated with atomics -> zero every call
    hipMemsetAsync(d_ws, 0, BC * KBINS * sizeof(int), stream);

    binloss_main<<<NBLOCKS, THREADS, 0, stream>>>(inp, tar, br, g_hist, partials);
    binloss_final<<<1, 256, 0, stream>>>(g_hist, partials, (float*)d_out);
}